// Round 7
// baseline (345.382 us; speedup 1.0000x reference)
//
#include <hip/hip_runtime.h>
#include <hip/hip_bf16.h>
#include <math.h>

#define B_   256
#define NPG_ 200
#define N0_  (B_*NPG_)     // 51200
#define DEGC 16
#define E_   (N0_*DEGC)    // 819200
#define SLOTG (NPG_*DEGC)  // 3200 edge slots per graph (original layout, never moved)
#define CSTRIDE 4096       // padded CSR slots per graph
#define CSRN (B_*CSTRIDE)
#define FIN_ 128
#define H_   256
#define K1_  100
#define K2_  50
#define K3_  25

// bijective XCD-chunk swizzle (m204)
__device__ __forceinline__ int xcd_swz(int bid, int nwg) {
    int q = nwg >> 3, r = nwg & 7;
    int x = bid & 7, j = bid >> 3;
    return (x < r ? x * (q + 1) : r * (q + 1) + (x - r) * q) + j;
}

__global__ void init_curmap_k(int* __restrict__ cm) {
    int i = blockIdx.x * 256 + threadIdx.x;
    if (i < N0_) cm[i] = i;
}

// ---------------- gemm_t: C[M x N] = A[M x K] @ W[K x N] (+bias/relu) ----------------
__global__ __launch_bounds__(256) void gemm_t(const float* __restrict__ A, const float* __restrict__ W,
                                              const float* __restrict__ bias, float* __restrict__ C,
                                              int M, int K, int N, int relu) {
    __shared__ float As[32][68];   // transposed: As[k][m]
    __shared__ float Bs[32][68];   // Bs[k][n]
    int t = threadIdx.x;
    int tx = t & 15, ty = t >> 4;
    int bm = xcd_swz(blockIdx.x, gridDim.x) * 64, bn = blockIdx.y * 64;
    int arow = t >> 2, akq = (t & 3) * 8;
    int brow = t >> 3, bnq = (t & 7) * 8;
    float acc[4][4] = {};
    for (int k0 = 0; k0 < K; k0 += 32) {
        float4 a0 = *(const float4*)&A[(size_t)(bm + arow) * K + k0 + akq];
        float4 a1 = *(const float4*)&A[(size_t)(bm + arow) * K + k0 + akq + 4];
        float4 b0 = *(const float4*)&W[(size_t)(k0 + brow) * N + bn + bnq];
        float4 b1 = *(const float4*)&W[(size_t)(k0 + brow) * N + bn + bnq + 4];
        As[akq + 0][arow] = a0.x; As[akq + 1][arow] = a0.y;
        As[akq + 2][arow] = a0.z; As[akq + 3][arow] = a0.w;
        As[akq + 4][arow] = a1.x; As[akq + 5][arow] = a1.y;
        As[akq + 6][arow] = a1.z; As[akq + 7][arow] = a1.w;
        *(float4*)&Bs[brow][bnq]     = b0;
        *(float4*)&Bs[brow][bnq + 4] = b1;
        __syncthreads();
        #pragma unroll
        for (int kk = 0; kk < 32; kk++) {
            float4 av = *(float4*)&As[kk][ty * 4];
            float4 bv = *(float4*)&Bs[kk][tx * 4];
            float a[4] = {av.x, av.y, av.z, av.w};
            float b[4] = {bv.x, bv.y, bv.z, bv.w};
            #pragma unroll
            for (int i = 0; i < 4; i++)
                #pragma unroll
                for (int j = 0; j < 4; j++) acc[i][j] += a[i] * b[j];
        }
        __syncthreads();
    }
    float bb[4] = {0.f, 0.f, 0.f, 0.f};
    if (bias) {
        #pragma unroll
        for (int j = 0; j < 4; j++) bb[j] = bias[bn + tx * 4 + j];
    }
    #pragma unroll
    for (int i = 0; i < 4; i++) {
        float4 c;
        c.x = acc[i][0] + bb[0]; c.y = acc[i][1] + bb[1];
        c.z = acc[i][2] + bb[2]; c.w = acc[i][3] + bb[3];
        if (relu) {
            c.x = fmaxf(c.x, 0.f); c.y = fmaxf(c.y, 0.f);
            c.z = fmaxf(c.z, 0.f); c.w = fmaxf(c.w, 0.f);
        }
        *(float4*)&C[(size_t)(bm + ty * 4 + i) * N + bn + tx * 4] = c;
    }
}

// -------- per-graph CSR build via CURMAP (edges never rewritten) --------
__global__ void csr_build_k(const int* __restrict__ esrc, const int* __restrict__ edst,
                            const int* __restrict__ curmap, int* __restrict__ offs,
                            int* __restrict__ offe, int* __restrict__ csrc,
                            float* __restrict__ coef, float* __restrict__ dinv, int npg) {
    __shared__ int   cml[256];
    __shared__ int   cnt[256];
    __shared__ int   sc[256];
    __shared__ int   pos[256];
    __shared__ float dv[256];
    __shared__ int   ecache[SLOTG];
    int g = xcd_swz(blockIdx.x, B_);
    int t = threadIdx.x;
    int ebase = g * SLOTG;
    int ob0 = g * NPG_;
    int nb0 = g * npg;
    int cbase = g * CSTRIDE;
    cml[t] = (t < NPG_) ? curmap[ob0 + t] : -1;
    cnt[t] = 0;
    __syncthreads();
    for (int e = t; e < SLOTG; e += 256) {
        int cs = cml[esrc[ebase + e] - ob0];
        int cd = cml[edst[ebase + e] - ob0];
        int pk = -1;
        if (cs >= 0 && cd >= 0) {
            int cs_l = cs - nb0, cd_l = cd - nb0;
            pk = cs_l | (cd_l << 8);
            atomicAdd(&cnt[cd_l], 1);
        }
        ecache[e] = pk;
    }
    __syncthreads();
    int v = (t < npg) ? cnt[t] : 0;
    float dloc = rsqrtf((float)v + 1.0f);
    dv[t] = dloc;
    int vp = (v + 3) & ~3;
    sc[t] = vp; __syncthreads();
    for (int d = 1; d < 256; d <<= 1) {
        int u = (t >= d) ? sc[t - d] : 0;
        __syncthreads();
        sc[t] += u;
        __syncthreads();
    }
    int excl = sc[t] - vp;
    pos[t] = cbase + excl;
    if (t < npg) {
        offs[nb0 + t] = cbase + excl;
        offe[nb0 + t] = cbase + excl + vp;
        dinv[nb0 + t] = dloc;
        for (int p = v; p < vp; p++) {
            csrc[cbase + excl + p] = nb0 + t;
            coef[cbase + excl + p] = 0.0f;
        }
    }
    __syncthreads();
    for (int e = t; e < SLOTG; e += 256) {
        int pk = ecache[e];
        if (pk >= 0) {
            int cs_l = pk & 255, cd_l = pk >> 8;
            int p = atomicAdd(&pos[cd_l], 1);
            csrc[p] = nb0 + cs_l;
            coef[p] = dv[cd_l] * dv[cs_l];
        }
    }
}

// ------- LDS-staged GCN aggregation: one block per (graph, feature-part) -------
// Stages the graph's XW slice (npg rows x FW feats) in LDS; all edge gathers hit LDS.
// Writes h (relu'd) and the partial score dot xsp[part*N0_ + node].
template<int FW>
__global__ __launch_bounds__(1024) void agg_lds_k(
        const float* __restrict__ xw, const int* __restrict__ offs,
        const int* __restrict__ offe, const int* __restrict__ csrc,
        const float* __restrict__ coef, const float* __restrict__ dinv,
        const float* __restrict__ bias, const float* __restrict__ Ws,
        float* __restrict__ h, float* __restrict__ xsp, int npg, int parts) {
    extern __shared__ float lds[];
    int gid = xcd_swz(blockIdx.x, gridDim.x);
    int g = gid / parts, part = gid - g * parts;
    int f0 = part * FW;
    int nb0 = g * npg;
    int t = threadIdx.x;
    // stage slice into LDS (packed [row][FW])
    int total4 = npg * (FW / 4);
    for (int i = t; i < total4; i += 1024) {
        int row = i / (FW / 4), c4 = i - row * (FW / 4);
        ((float4*)lds)[i] = *(const float4*)&xw[(size_t)(nb0 + row) * H_ + f0 + c4 * 4];
    }
    __syncthreads();
    int wid = t >> 6, lane = t & 63;
    if constexpr (FW == 128) {
        const float2* ld2 = (const float2*)lds;
        float2 bb  = *(const float2*)&bias[f0 + lane * 2];
        float2 wsr = *(const float2*)&Ws[f0 + lane * 2];
        for (int nl = wid; nl < npg; nl += 16) {
            int node = nb0 + nl;
            float dd = dinv[node];
            int e0 = offs[node], e1 = offe[node];
            float ax = 0.f, ay = 0.f;
            for (int j = e0; j < e1; j += 4) {
                int4   s4 = *(const int4*)&csrc[j];
                float4 c4 = *(const float4*)&coef[j];
                float2 v0 = ld2[(s4.x - nb0) * 64 + lane];
                float2 v1 = ld2[(s4.y - nb0) * 64 + lane];
                float2 v2 = ld2[(s4.z - nb0) * 64 + lane];
                float2 v3 = ld2[(s4.w - nb0) * 64 + lane];
                ax += c4.x * v0.x + c4.y * v1.x + c4.z * v2.x + c4.w * v3.x;
                ay += c4.x * v0.y + c4.y * v1.y + c4.z * v2.y + c4.w * v3.y;
            }
            float2 self = ld2[nl * 64 + lane];
            float s2 = dd * dd;
            float rx = fmaxf(ax + self.x * s2 + bb.x, 0.f);
            float ry = fmaxf(ay + self.y * s2 + bb.y, 0.f);
            float2 r2; r2.x = rx; r2.y = ry;
            *(float2*)&h[(size_t)node * H_ + f0 + lane * 2] = r2;
            float p = rx * wsr.x + ry * wsr.y;
            #pragma unroll
            for (int d = 32; d > 0; d >>= 1) p += __shfl_down(p, d);
            if (lane == 0) xsp[part * N0_ + node] = p;
        }
    } else {  // FW == 256
        const float4* ld4 = (const float4*)lds;
        float4 bb  = *(const float4*)&bias[lane * 4];
        float4 wsr = *(const float4*)&Ws[lane * 4];
        for (int nl = wid; nl < npg; nl += 16) {
            int node = nb0 + nl;
            float dd = dinv[node];
            int e0 = offs[node], e1 = offe[node];
            float ax = 0.f, ay = 0.f, az = 0.f, aw = 0.f;
            for (int j = e0; j < e1; j += 4) {
                int4   s4 = *(const int4*)&csrc[j];
                float4 c4 = *(const float4*)&coef[j];
                float4 v0 = ld4[(s4.x - nb0) * 64 + lane];
                float4 v1 = ld4[(s4.y - nb0) * 64 + lane];
                float4 v2 = ld4[(s4.z - nb0) * 64 + lane];
                float4 v3 = ld4[(s4.w - nb0) * 64 + lane];
                ax += c4.x * v0.x + c4.y * v1.x + c4.z * v2.x + c4.w * v3.x;
                ay += c4.x * v0.y + c4.y * v1.y + c4.z * v2.y + c4.w * v3.y;
                az += c4.x * v0.z + c4.y * v1.z + c4.z * v2.z + c4.w * v3.z;
                aw += c4.x * v0.w + c4.y * v1.w + c4.z * v2.w + c4.w * v3.w;
            }
            float4 self = ld4[nl * 64 + lane];
            float s2 = dd * dd;
            float4 r;
            r.x = fmaxf(ax + self.x * s2 + bb.x, 0.f);
            r.y = fmaxf(ay + self.y * s2 + bb.y, 0.f);
            r.z = fmaxf(az + self.z * s2 + bb.z, 0.f);
            r.w = fmaxf(aw + self.w * s2 + bb.w, 0.f);
            *(float4*)&h[(size_t)node * H_ + lane * 4] = r;
            float p = r.x * wsr.x + r.y * wsr.y + r.z * wsr.z + r.w * wsr.w;
            #pragma unroll
            for (int d = 32; d > 0; d >>= 1) p += __shfl_down(p, d);
            if (lane == 0) xsp[node] = p;
        }
    }
}

// -------- fused score GCN + top-k + pool + readout + CURMAP compose --------
__global__ void score_topk_pool_k(const float* __restrict__ h, const float* __restrict__ xsp,
                                  const int* __restrict__ offs, const int* __restrict__ offe,
                                  const int* __restrict__ csrc, const float* __restrict__ coef,
                                  const float* __restrict__ dinv, const float* __restrict__ bs,
                                  int* __restrict__ curmap, float* __restrict__ ph,
                                  float* __restrict__ z, int npg, int k, int accumulate, int parts) {
    __shared__ float xsl[256];
    __shared__ float sc[256];
    __shared__ int   id[256];
    __shared__ int   rl[256];
    __shared__ int   ps[128];
    __shared__ float ts[128];
    int g = xcd_swz(blockIdx.x, B_);
    int t = threadIdx.x;
    int nb0 = g * npg;
    float xv = 0.f;
    if (t < npg) {
        xv = xsp[nb0 + t];
        if (parts == 2) xv += xsp[N0_ + nb0 + t];
    }
    xsl[t] = xv;
    rl[t] = -1;
    __syncthreads();
    float scv = -INFINITY;
    if (t < npg) {
        int gi = nb0 + t;
        float dd = dinv[gi];
        float acc = 0.f;
        for (int j = offs[gi]; j < offe[gi]; j++)
            acc += coef[j] * xsl[csrc[j] - nb0];
        scv = acc + xsl[t] * dd * dd + bs[0];
    }
    sc[t] = scv;
    id[t] = (t < npg) ? t : 0x7fffffff;
    __syncthreads();
    for (int ksz = 2; ksz <= 256; ksz <<= 1) {
        for (int j = ksz >> 1; j > 0; j >>= 1) {
            int ixj = t ^ j;
            if (ixj > t) {
                float s1 = sc[t], s2 = sc[ixj];
                int i1 = id[t], i2 = id[ixj];
                bool asc = ((t & ksz) == 0);
                bool agtb = (s1 < s2) || (s1 == s2 && i1 > i2);
                if (asc ? agtb : !agtb) { sc[t] = s2; sc[ixj] = s1; id[t] = i2; id[ixj] = i1; }
            }
            __syncthreads();
        }
    }
    if (t < k) {
        rl[id[t]] = g * k + t;
        ps[t] = nb0 + id[t];
        ts[t] = tanhf(sc[t]);
    }
    __syncthreads();
    if (t < NPG_) {
        int o = g * NPG_ + t;
        int old = curmap[o];
        curmap[o] = (old < 0) ? -1 : rl[old - nb0];
    }
    float mx = -INFINITY, sm = 0.f;
    for (int j = 0; j < k; j++) {
        float v = h[(size_t)ps[j] * H_ + t] * ts[j];
        ph[(size_t)(g * k + j) * H_ + t] = v;
        mx = fmaxf(mx, v); sm += v;
    }
    float mean = sm / (float)k;
    if (accumulate) { z[g * 512 + t] += mx; z[g * 512 + 256 + t] += mean; }
    else            { z[g * 512 + t]  = mx; z[g * 512 + 256 + t]  = mean; }
}

// ---------------- fused MLP layer-3 + log_softmax ----------------
__global__ void mlp3_lsm_k(const float* __restrict__ A, const float* __restrict__ W,
                           const float* __restrict__ bias, float* __restrict__ out) {
    int m = blockIdx.x, l = threadIdx.x;
    float a0 = A[m * 128 + l], a1 = A[m * 128 + 64 + l];
    float r[10];
    #pragma unroll
    for (int n = 0; n < 10; n++) r[n] = a0 * W[l * 10 + n] + a1 * W[(l + 64) * 10 + n];
    #pragma unroll
    for (int d = 1; d < 64; d <<= 1)
        #pragma unroll
        for (int n = 0; n < 10; n++) r[n] += __shfl_xor(r[n], d);
    float v[10]; float mx = -INFINITY;
    #pragma unroll
    for (int n = 0; n < 10; n++) { v[n] = r[n] + bias[n]; mx = fmaxf(mx, v[n]); }
    float s = 0.f;
    #pragma unroll
    for (int n = 0; n < 10; n++) s += expf(v[n] - mx);
    float ls = logf(s);
    if (l < 10) out[m * 10 + l] = v[l] - mx - ls;
}

extern "C" void kernel_launch(void* const* d_in, const int* in_sizes, int n_in,
                              void* d_out, int out_size, void* d_ws, size_t ws_size,
                              hipStream_t stream) {
    const float* x   = (const float*)d_in[0];
    const int*  esrc = (const int*) d_in[1];
    const int*  edst = (const int*) d_in[2];
    const float *W1 = (const float*)d_in[3],  *b1 = (const float*)d_in[4];
    const float *Ws1= (const float*)d_in[5],  *bs1= (const float*)d_in[6];
    const float *W2 = (const float*)d_in[7],  *b2 = (const float*)d_in[8];
    const float *Ws2= (const float*)d_in[9],  *bs2= (const float*)d_in[10];
    const float *W3 = (const float*)d_in[11], *b3 = (const float*)d_in[12];
    const float *Ws3= (const float*)d_in[13], *bs3= (const float*)d_in[14];
    const float *Wl1= (const float*)d_in[15], *bl1= (const float*)d_in[16];
    const float *Wl2= (const float*)d_in[17], *bl2= (const float*)d_in[18];
    const float *Wl3= (const float*)d_in[19], *bl3= (const float*)d_in[20];
    float* out = (float*)d_out;

    // ---- workspace layout ----
    float* ws = (float*)d_ws;
    float* XW    = ws;                         // N0*H
    float* Hb    = XW + (size_t)N0_ * H_;      // N0*H
    float* PH    = Hb + (size_t)N0_ * H_;      // (B*K1)*H
    float* DINV  = PH + (size_t)B_ * K1_ * H_; // N0
    float* XSP   = DINV + N0_;                 // 2*N0
    int*   CURMAP= (int*)(XSP + 2 * N0_);      // N0
    int*   OFFS  = CURMAP + N0_;               // N0
    int*   OFFE  = OFFS + N0_;                 // N0
    int*   CSRC  = OFFE + N0_;                 // CSRN
    float* COEF  = (float*)(CSRC + CSRN);      // CSRN
    float* Z     = COEF + CSRN;                // B*512
    float* Z1    = Z + B_ * 512;               // B*256
    float* Z2    = Z1 + B_ * 256;              // B*128

    init_curmap_k<<<N0_ / 256, 256, 0, stream>>>(CURMAP);

    const int npgs[3]  = { NPG_, K1_, K2_ };
    const int ks[3]    = { K1_, K2_, K3_ };
    const float* Wm[3]  = { W1, W2, W3 };
    const float* bm[3]  = { b1, b2, b3 };
    const float* Wsm[3] = { Ws1, Ws2, Ws3 };
    const float* bsm[3] = { bs1, bs2, bs3 };

    for (int st = 0; st < 3; st++) {
        int npg = npgs[st], k = ks[st];
        int n = B_ * npg;

        // 1. xw = X @ W
        if (st == 0)
            gemm_t<<<dim3(n / 64, H_ / 64), 256, 0, stream>>>(x, Wm[st], nullptr, XW, n, FIN_, H_, 0);
        else
            gemm_t<<<dim3(n / 64, H_ / 64), 256, 0, stream>>>(PH, Wm[st], nullptr, XW, n, H_, H_, 0);

        // 2. per-graph padded CSR build from original edges + CURMAP
        csr_build_k<<<B_, 256, 0, stream>>>(esrc, edst, CURMAP, OFFS, OFFE, CSRC, COEF, DINV, npg);

        // 3. LDS-staged aggregation: h = relu(agg + self + b), partial xs = h.Ws
        if (st == 0)
            agg_lds_k<128><<<2 * B_, 1024, NPG_ * 128 * 4, stream>>>(
                XW, OFFS, OFFE, CSRC, COEF, DINV, bm[st], Wsm[st], Hb, XSP, npg, 2);
        else
            agg_lds_k<256><<<B_, 1024, npg * 256 * 4, stream>>>(
                XW, OFFS, OFFE, CSRC, COEF, DINV, bm[st], Wsm[st], Hb, XSP, npg, 1);

        // 4-7. score GCN + top-k + pool + readout + CURMAP compose
        score_topk_pool_k<<<B_, 256, 0, stream>>>(Hb, XSP, OFFS, OFFE, CSRC, COEF, DINV, bsm[st],
                                                  CURMAP, PH, Z, npg, k, st > 0 ? 1 : 0,
                                                  st == 0 ? 2 : 1);
    }

    // ---- MLP head ----
    gemm_t<<<dim3(B_ / 64, 256 / 64), 256, 0, stream>>>(Z,  Wl1, bl1, Z1, B_, 512, 256, 1);
    gemm_t<<<dim3(B_ / 64, 128 / 64), 256, 0, stream>>>(Z1, Wl2, bl2, Z2, B_, 256, 128, 1);
    mlp3_lsm_k<<<B_, 64, 0, stream>>>(Z2, Wl3, bl3, out);
}